// Round 4
// baseline (365.280 us; speedup 1.0000x reference)
//
#include <hip/hip_runtime.h>

// TripletLoss: pairs (2i,2i+1); label[2i]==0 -> row 2i positive.
// loss = mean_i relu(d(proto,pos_i) - d(proto,neg_i) + margin), fp32 scalar.
//
// R4: wave-per-row coalesced float4 loads; 4 pairs/iter reduced with a
// reduce-scatter (2 select+shuffle steps scatter 4 sums into disjoint
// 16-lane groups, then 4 shared DPP-class butterfly steps finish all 4 at
// once: 7 shuffles per 4 pairs vs 24). Pair sign applied AFTER reduction
// (linear), per-lane group sign preloaded. 32 pairs/wave, 8 unrolled iters
// with 2-stage prefetch; 1024 blocks == fully resident grid at 4 waves/EU.
// Deterministic: block partials -> d_ws, tiny finish kernel.

#define BLOCK_THREADS 256
#define WAVES_PER_BLOCK 4
#define ITERS 8                    // 4 pairs per iter -> 32 pairs per wave
#define PAIRS_PER_WAVE 32

__global__ __launch_bounds__(BLOCK_THREADS, 4) void tl_main(
    const float* __restrict__ proto,
    const float* __restrict__ emb,
    const int* __restrict__ label,
    const int* __restrict__ margin_p,
    float* __restrict__ partial,
    int n_pairs)
{
    __shared__ float swave[WAVES_PER_BLOCK];

    const int lane = threadIdx.x & 63;
    const int wv   = threadIdx.x >> 6;
    const int wave = blockIdx.x * WAVES_PER_BLOCK + wv;
    const int pair_base = wave * PAIRS_PER_WAVE;

    // margin: robust to int32 or fp32 storage of the Python scalar 1
    int mbits = margin_p[0];
    const float margin = (mbits >= -1000000 && mbits <= 1000000)
                             ? (float)mbits
                             : __int_as_float(mbits);

    // lane l holds proto[4l..4l+3]
    const float4 p = ((const float4*)proto)[lane];

    // group -> pair-in-iter permutation from the reduce-scatter: [0,2,1,3]
    const int g  = lane >> 4;
    const int pg = ((g & 1) << 1) | (g >> 1);

    // preload this lane's group-pair sign for every iteration
    float sg[ITERS];
    #pragma unroll
    for (int it = 0; it < ITERS; ++it) {
        const int lb = label[2 * (pair_base + it * 4 + pg)];
        sg[it] = (lb == 0) ? 1.0f : -1.0f;
    }

    const float4* __restrict__ rows =
        (const float4*)(emb + (size_t)pair_base * 2 * 256);

    // prime batch 0: 8 rows (4 pairs), float4 index of row r = r*64 + lane
    float4 x[8];
    #pragma unroll
    for (int r = 0; r < 8; ++r) x[r] = rows[r * 64 + lane];

    const float gmask = ((lane & 15) == 0) ? 1.0f : 0.0f;
    const bool hi32 = (lane & 32) != 0;
    const bool hi16 = (lane & 16) != 0;

    float acc = 0.0f;

    #pragma unroll
    for (int it = 0; it < ITERS; ++it) {
        float4 y[8];
        if (it + 1 < ITERS) {
            const float4* nr = rows + (size_t)(it + 1) * 8 * 64;
            #pragma unroll
            for (int r = 0; r < 8; ++r) y[r] = nr[r * 64 + lane];
        }

        // per-lane unsigned delta (d_even - d_odd) for the 4 pairs
        float s[4];
        #pragma unroll
        for (int q = 0; q < 4; ++q) {
            const float4 e0 = x[2 * q];
            const float4 e1 = x[2 * q + 1];
            float dx, d0, d1;
            dx = p.x - e0.x; d0 = dx * dx;
            dx = p.y - e0.y; d0 = fmaf(dx, dx, d0);
            dx = p.z - e0.z; d0 = fmaf(dx, dx, d0);
            dx = p.w - e0.w; d0 = fmaf(dx, dx, d0);
            dx = p.x - e1.x; d1 = dx * dx;
            dx = p.y - e1.y; d1 = fmaf(dx, dx, d1);
            dx = p.z - e1.z; d1 = fmaf(dx, dx, d1);
            dx = p.w - e1.w; d1 = fmaf(dx, dx, d1);
            s[q] = d0 - d1;
        }

        // reduce-scatter step A (offset 32): pairs {0,1} -> u, {2,3} -> v
        const float tA0 = hi32 ? s[0] : s[1];
        const float rA0 = __shfl_xor(tA0, 32, 64);
        float u = (hi32 ? s[1] : s[0]) + rA0;

        const float tA1 = hi32 ? s[2] : s[3];
        const float rA1 = __shfl_xor(tA1, 32, 64);
        float v = (hi32 ? s[3] : s[2]) + rA1;

        // step B (offset 16): scatter into 16-lane groups [p0|p2|p1|p3]
        const float tB = hi16 ? u : v;
        const float rB = __shfl_xor(tB, 16, 64);
        float w = (hi16 ? v : u) + rB;

        // shared tail: 4 butterfly steps reduce all 4 groups at once
        w += __shfl_xor(w, 8, 64);
        w += __shfl_xor(w, 4, 64);
        w += __shfl_xor(w, 2, 64);
        w += __shfl_xor(w, 1, 64);

        // apply this group's pair sign, margin, relu; count once per group
        const float loss = fmaf(sg[it], w, margin);
        acc = fmaf(gmask, fmaxf(loss, 0.0f), acc);

        if (it + 1 < ITERS) {
            #pragma unroll
            for (int r = 0; r < 8; ++r) x[r] = y[r];
        }
    }

    // wave total (acc nonzero only on lanes 0,16,32,48)
    #pragma unroll
    for (int off = 32; off > 0; off >>= 1)
        acc += __shfl_xor(acc, off, 64);

    if (lane == 0) swave[wv] = acc;
    __syncthreads();

    if (threadIdx.x == 0)
        partial[blockIdx.x] = (swave[0] + swave[1]) + (swave[2] + swave[3]);
}

__global__ __launch_bounds__(256) void tl_finish(
    const float* __restrict__ partial, float* __restrict__ out,
    int n_blocks, float inv_count)
{
    __shared__ float sw[4];
    float v = 0.0f;
    for (int i = threadIdx.x; i < n_blocks; i += 256) v += partial[i];

    #pragma unroll
    for (int off = 32; off > 0; off >>= 1)
        v += __shfl_xor(v, off, 64);

    const int lane = threadIdx.x & 63;
    const int wv = threadIdx.x >> 6;
    if (lane == 0) sw[wv] = v;
    __syncthreads();

    if (threadIdx.x == 0)
        out[0] = ((sw[0] + sw[1]) + (sw[2] + sw[3])) * inv_count;
}

extern "C" void kernel_launch(void* const* d_in, const int* in_sizes, int n_in,
                              void* d_out, int out_size, void* d_ws, size_t ws_size,
                              hipStream_t stream) {
    const float* proto = (const float*)d_in[0];
    const float* emb   = (const float*)d_in[1];
    const int*   label = (const int*)d_in[2];
    const int*   marg  = (const int*)d_in[3];
    float* out = (float*)d_out;
    float* partial = (float*)d_ws;

    const int n_rows  = in_sizes[2];      // 262144
    const int n_pairs = n_rows / 2;       // 131072

    // each block: 4 waves x 32 pairs x 2 rows = 256 rows
    const int blocks = n_rows / (WAVES_PER_BLOCK * PAIRS_PER_WAVE * 2); // 1024
    tl_main<<<blocks, BLOCK_THREADS, 0, stream>>>(proto, emb, label, marg,
                                                  partial, n_pairs);
    tl_finish<<<1, 256, 0, stream>>>(partial, out, blocks,
                                     1.0f / (float)n_pairs);
}

// Round 5
// 362.363 us; speedup vs baseline: 1.0080x; 1.0080x over previous
//
#include <hip/hip_runtime.h>

// TripletLoss: pairs (2i,2i+1); label[2i]==0 -> row 2i positive.
// loss = mean_i relu(d(proto,pos_i) - d(proto,neg_i) + margin), fp32 scalar.
//
// R5 = R4 compute with STEP-MAJOR pair mapping. R4 gave each wave a private
// 64KB chunk -> at any instant the grid's concurrent reads are 64KB-strided
// (power-of-2) -> HBM channel camping. Here, step s assigns wave w pairs
// s*16384 + 4w + q: the whole grid reads one contiguous 32MB window per
// step, sweeping memory like the 6.7 TB/s fill kernel does.
// Reduce-scatter: 2 select+shuffle steps scatter 4 pair-sums into disjoint
// 16-lane groups, 4 shared butterfly steps finish; sign applied post-
// reduction (linear). Deterministic finish via d_ws partials.

#define BLOCK_THREADS 256
#define WAVES_PER_BLOCK 4
#define NUM_BLOCKS 1024
#define TOTAL_WAVES (NUM_BLOCKS * WAVES_PER_BLOCK)   // 4096
#define STEPS 8                                      // 131072 pairs / (4096*4)

__global__ __launch_bounds__(BLOCK_THREADS, 4) void tl_main(
    const float* __restrict__ proto,
    const float* __restrict__ emb,
    const int* __restrict__ label,
    const int* __restrict__ margin_p,
    float* __restrict__ partial,
    int n_pairs)
{
    __shared__ float swave[WAVES_PER_BLOCK];

    const int lane = threadIdx.x & 63;
    const int wv   = threadIdx.x >> 6;
    const int wave = blockIdx.x * WAVES_PER_BLOCK + wv;

    // margin: robust to int32 or fp32 storage of the Python scalar 1
    int mbits = margin_p[0];
    const float margin = (mbits >= -1000000 && mbits <= 1000000)
                             ? (float)mbits
                             : __int_as_float(mbits);

    // lane l holds proto[4l..4l+3]
    const float4 p = ((const float4*)proto)[lane];

    // group -> pair-in-step permutation from the reduce-scatter: [0,2,1,3]
    const int g  = lane >> 4;
    const int pg = ((g & 1) << 1) | (g >> 1);

    // preload this lane's group-pair sign for every step
    float sg[STEPS];
    #pragma unroll
    for (int s = 0; s < STEPS; ++s) {
        const int pr = s * (TOTAL_WAVES * 4) + wave * 4 + pg;
        sg[s] = (label[2 * pr] == 0) ? 1.0f : -1.0f;
    }

    // step s, this wave: 8 contiguous rows starting at pair s*16384 + 4*wave
    // float4 row index of row r = r*64 + lane
    const float4* __restrict__ base =
        (const float4*)(emb + (size_t)wave * 4 * 2 * 256);
    const size_t step_stride = (size_t)TOTAL_WAVES * 4 * 2 * 64; // float4s/step

    // prime step 0
    float4 x[8];
    #pragma unroll
    for (int r = 0; r < 8; ++r) x[r] = base[r * 64 + lane];

    const float gmask = ((lane & 15) == 0) ? 1.0f : 0.0f;
    const bool hi32 = (lane & 32) != 0;
    const bool hi16 = (lane & 16) != 0;

    float acc = 0.0f;

    #pragma unroll
    for (int s = 0; s < STEPS; ++s) {
        float4 y[8];
        if (s + 1 < STEPS) {
            const float4* nr = base + (size_t)(s + 1) * step_stride;
            #pragma unroll
            for (int r = 0; r < 8; ++r) y[r] = nr[r * 64 + lane];
        }

        // per-lane unsigned delta (d_even - d_odd) for the 4 pairs
        float sdel[4];
        #pragma unroll
        for (int q = 0; q < 4; ++q) {
            const float4 e0 = x[2 * q];
            const float4 e1 = x[2 * q + 1];
            float dx, d0, d1;
            dx = p.x - e0.x; d0 = dx * dx;
            dx = p.y - e0.y; d0 = fmaf(dx, dx, d0);
            dx = p.z - e0.z; d0 = fmaf(dx, dx, d0);
            dx = p.w - e0.w; d0 = fmaf(dx, dx, d0);
            dx = p.x - e1.x; d1 = dx * dx;
            dx = p.y - e1.y; d1 = fmaf(dx, dx, d1);
            dx = p.z - e1.z; d1 = fmaf(dx, dx, d1);
            dx = p.w - e1.w; d1 = fmaf(dx, dx, d1);
            sdel[q] = d0 - d1;
        }

        // reduce-scatter step A (offset 32): pairs {0,1} -> u, {2,3} -> v
        const float tA0 = hi32 ? sdel[0] : sdel[1];
        const float rA0 = __shfl_xor(tA0, 32, 64);
        float u = (hi32 ? sdel[1] : sdel[0]) + rA0;

        const float tA1 = hi32 ? sdel[2] : sdel[3];
        const float rA1 = __shfl_xor(tA1, 32, 64);
        float v = (hi32 ? sdel[3] : sdel[2]) + rA1;

        // step B (offset 16): scatter into 16-lane groups [p0|p2|p1|p3]
        const float tB = hi16 ? u : v;
        const float rB = __shfl_xor(tB, 16, 64);
        float w = (hi16 ? v : u) + rB;

        // shared tail: 4 butterfly steps reduce all 4 groups at once
        w += __shfl_xor(w, 8, 64);
        w += __shfl_xor(w, 4, 64);
        w += __shfl_xor(w, 2, 64);
        w += __shfl_xor(w, 1, 64);

        // apply this group's pair sign, margin, relu; count once per group
        const float loss = fmaf(sg[s], w, margin);
        acc = fmaf(gmask, fmaxf(loss, 0.0f), acc);

        if (s + 1 < STEPS) {
            #pragma unroll
            for (int r = 0; r < 8; ++r) x[r] = y[r];
        }
    }

    // wave total (acc nonzero only on lanes 0,16,32,48)
    #pragma unroll
    for (int off = 32; off > 0; off >>= 1)
        acc += __shfl_xor(acc, off, 64);

    if (lane == 0) swave[wv] = acc;
    __syncthreads();

    if (threadIdx.x == 0)
        partial[blockIdx.x] = (swave[0] + swave[1]) + (swave[2] + swave[3]);
}

__global__ __launch_bounds__(256) void tl_finish(
    const float* __restrict__ partial, float* __restrict__ out,
    int n_blocks, float inv_count)
{
    __shared__ float sw[4];
    float v = 0.0f;
    for (int i = threadIdx.x; i < n_blocks; i += 256) v += partial[i];

    #pragma unroll
    for (int off = 32; off > 0; off >>= 1)
        v += __shfl_xor(v, off, 64);

    const int lane = threadIdx.x & 63;
    const int wv = threadIdx.x >> 6;
    if (lane == 0) sw[wv] = v;
    __syncthreads();

    if (threadIdx.x == 0)
        out[0] = ((sw[0] + sw[1]) + (sw[2] + sw[3])) * inv_count;
}

extern "C" void kernel_launch(void* const* d_in, const int* in_sizes, int n_in,
                              void* d_out, int out_size, void* d_ws, size_t ws_size,
                              hipStream_t stream) {
    const float* proto = (const float*)d_in[0];
    const float* emb   = (const float*)d_in[1];
    const int*   label = (const int*)d_in[2];
    const int*   marg  = (const int*)d_in[3];
    float* out = (float*)d_out;
    float* partial = (float*)d_ws;

    const int n_rows  = in_sizes[2];      // 262144
    const int n_pairs = n_rows / 2;       // 131072

    tl_main<<<NUM_BLOCKS, BLOCK_THREADS, 0, stream>>>(proto, emb, label, marg,
                                                      partial, n_pairs);
    tl_finish<<<1, 256, 0, stream>>>(partial, out, NUM_BLOCKS,
                                     1.0f / (float)n_pairs);
}

// Round 6
// 360.367 us; speedup vs baseline: 1.0136x; 1.0055x over previous
//
#include <hip/hip_runtime.h>

// TripletLoss: pairs (2i,2i+1); label[2i]==0 -> row 2i positive.
// loss = mean_i relu(d(proto,pos_i) - d(proto,neg_i) + margin), fp32 scalar.
//
// R6: MLP/occupancy experiment. R3/R4/R5 proved the plateau (~2.6 TB/s) is
// insensitive to address pattern and shuffle count -> outstanding-request
// (memory-level-parallelism) bound. This round: 32 waves/CU (2048 blocks,
// __launch_bounds__(256,8), VGPR budget ~50 <= 64), 4KB double-buffered
// rounds so every wave always has loads in flight. Labels: one per-lane
// sign preload + __shfl(const) broadcast, zero per-round label loads.
// Reduction: 1 select+shuffle(32) + 5 shared butterflies per 2 pairs.

#define BLOCK_THREADS 256
#define WAVES_PER_BLOCK 4
#define ROUNDS 8                   // 2 pairs (4 rows, 4 KB) per round
#define PAIRS_PER_WAVE (2 * ROUNDS)

__global__ __launch_bounds__(BLOCK_THREADS, 8) void tl_main(
    const float* __restrict__ proto,
    const float* __restrict__ emb,
    const int* __restrict__ label,
    const int* __restrict__ margin_p,
    float* __restrict__ partial)
{
    __shared__ float swave[WAVES_PER_BLOCK];

    const int lane = threadIdx.x & 63;
    const int wv   = threadIdx.x >> 6;
    const int wave = blockIdx.x * WAVES_PER_BLOCK + wv;
    const int pair_base = wave * PAIRS_PER_WAVE;

    // margin: robust to int32 or fp32 storage of the Python scalar 1
    int mbits = margin_p[0];
    const float margin = (mbits >= -1000000 && mbits <= 1000000)
                             ? (float)mbits
                             : __int_as_float(mbits);

    // lane l holds proto[4l..4l+3]
    const float4 p = ((const float4*)proto)[lane];

    // lane k (k<16) holds the sign of pair (pair_base + k): +1 if even row
    // is the positive (label==0), else -1. Broadcast per round via shfl.
    const int lb = label[2 * (pair_base + (lane & 15))];
    const float sgn_lane = 1.0f - 2.0f * (float)lb;

    // this wave's 32 contiguous rows (32 KB)
    const float4* __restrict__ base =
        (const float4*)(emb + (size_t)pair_base * 2 * 256);

    // prime round 0: 4 rows (2 pairs, 4 KB); float4 idx of row r = r*64+lane
    float4 x[4];
    #pragma unroll
    for (int r = 0; r < 4; ++r) x[r] = base[r * 64 + lane];

    const bool hi32 = (lane & 32) != 0;
    const float m32 = ((lane & 31) == 0) ? 1.0f : 0.0f;

    float acc = 0.0f;

    #pragma unroll
    for (int t = 0; t < ROUNDS; ++t) {
        float4 y[4];
        if (t + 1 < ROUNDS) {
            const float4* nb = base + (size_t)(t + 1) * 256;
            #pragma unroll
            for (int r = 0; r < 4; ++r) y[r] = nb[r * 64 + lane];
        }

        // per-lane squared-distance partials for the 4 rows
        float dx;
        float d0, d1, d2, d3;
        dx = p.x - x[0].x; d0 = dx * dx;
        dx = p.y - x[0].y; d0 = fmaf(dx, dx, d0);
        dx = p.z - x[0].z; d0 = fmaf(dx, dx, d0);
        dx = p.w - x[0].w; d0 = fmaf(dx, dx, d0);
        dx = p.x - x[1].x; d1 = dx * dx;
        dx = p.y - x[1].y; d1 = fmaf(dx, dx, d1);
        dx = p.z - x[1].z; d1 = fmaf(dx, dx, d1);
        dx = p.w - x[1].w; d1 = fmaf(dx, dx, d1);
        dx = p.x - x[2].x; d2 = dx * dx;
        dx = p.y - x[2].y; d2 = fmaf(dx, dx, d2);
        dx = p.z - x[2].z; d2 = fmaf(dx, dx, d2);
        dx = p.w - x[2].w; d2 = fmaf(dx, dx, d2);
        dx = p.x - x[3].x; d3 = dx * dx;
        dx = p.y - x[3].y; d3 = fmaf(dx, dx, d3);
        dx = p.z - x[3].z; d3 = fmaf(dx, dx, d3);
        dx = p.w - x[3].w; d3 = fmaf(dx, dx, d3);

        // signed per-lane deltas for pair A (rows 0,1) and pair B (rows 2,3)
        const float sA = __shfl(sgn_lane, 2 * t, 64);
        const float sB = __shfl(sgn_lane, 2 * t + 1, 64);
        const float a = sA * (d0 - d1);
        const float b = sB * (d2 - d3);

        // select+shuffle(32): lanes 0-31 -> pair A, lanes 32-63 -> pair B
        const float tsel = hi32 ? a : b;
        const float rsel = __shfl_xor(tsel, 32, 64);
        float w = (hi32 ? b : a) + rsel;
        // shared tail: both 32-lane groups reduce simultaneously
        w += __shfl_xor(w, 16, 64);
        w += __shfl_xor(w, 8, 64);
        w += __shfl_xor(w, 4, 64);
        w += __shfl_xor(w, 2, 64);
        w += __shfl_xor(w, 1, 64);

        // lanes 0 and 32 hold the two pair deltas
        acc = fmaf(m32, fmaxf(w + margin, 0.0f), acc);

        if (t + 1 < ROUNDS) {
            #pragma unroll
            for (int r = 0; r < 4; ++r) x[r] = y[r];
        }
    }

    // combine lanes 0 and 32
    acc += __shfl_xor(acc, 32, 64);

    if (lane == 0) swave[wv] = acc;
    __syncthreads();

    if (threadIdx.x == 0)
        partial[blockIdx.x] = (swave[0] + swave[1]) + (swave[2] + swave[3]);
}

__global__ __launch_bounds__(256) void tl_finish(
    const float* __restrict__ partial, float* __restrict__ out,
    int n_blocks, float inv_count)
{
    __shared__ float sw[4];
    float v = 0.0f;
    for (int i = threadIdx.x; i < n_blocks; i += 256) v += partial[i];

    #pragma unroll
    for (int off = 32; off > 0; off >>= 1)
        v += __shfl_xor(v, off, 64);

    const int lane = threadIdx.x & 63;
    const int wv = threadIdx.x >> 6;
    if (lane == 0) sw[wv] = v;
    __syncthreads();

    if (threadIdx.x == 0)
        out[0] = ((sw[0] + sw[1]) + (sw[2] + sw[3])) * inv_count;
}

extern "C" void kernel_launch(void* const* d_in, const int* in_sizes, int n_in,
                              void* d_out, int out_size, void* d_ws, size_t ws_size,
                              hipStream_t stream) {
    const float* proto = (const float*)d_in[0];
    const float* emb   = (const float*)d_in[1];
    const int*   label = (const int*)d_in[2];
    const int*   marg  = (const int*)d_in[3];
    float* out = (float*)d_out;
    float* partial = (float*)d_ws;

    const int n_rows  = in_sizes[2];      // 262144
    const int n_pairs = n_rows / 2;       // 131072

    // each block: 4 waves x 16 pairs x 2 rows = 128 rows -> 2048 blocks
    const int blocks = n_rows / (WAVES_PER_BLOCK * PAIRS_PER_WAVE * 2);
    tl_main<<<blocks, BLOCK_THREADS, 0, stream>>>(proto, emb, label, marg,
                                                  partial);
    tl_finish<<<1, 256, 0, stream>>>(partial, out, blocks,
                                     1.0f / (float)n_pairs);
}